// Round 4
// baseline (154.213 us; speedup 1.0000x reference)
//
#include <hip/hip_runtime.h>
#include <hip/hip_bf16.h>

// GAT layer: B=8, N=2048, Fin=256, Fout=128  (f32 in / f32 out)
// Wh = h@W ; s1 = Wh@a1 ; s2 = Wh@a2
// P[i,j] = softmax_i( lrelu(s1_i+s2_j) ) ; out = elu(P @ Wh)
// R4: WhT stored in 32jx128d tiles -> k_pv B-frag loads are 1KB contiguous.
//     Softmax in base-2 domain (s1,s2 pre-scaled by log2e; l2z = -m - log2 Z).

#define ALPHA 0.2f
#define LOG2E 1.4426950408889634f
constexpr int Bb=8, Nn=2048, FIN=256, FOUT=128;

typedef __attribute__((ext_vector_type(8))) short short8;
typedef __attribute__((ext_vector_type(4))) float f32x4;

__device__ __forceinline__ float lrelu(float x){ return fmaxf(x, ALPHA*x); }
__device__ __forceinline__ short bfbits(float x){
    __hip_bfloat16 h = __float2bfloat16(x);
    return *(short*)&h;
}

// ---- K1: Wh rows (f32) -> s1,s2 (xLOG2E), WhT tiles [b][jt][d][32] bf16 ----
__global__ __launch_bounds__(256) void k_wh(const float* __restrict__ h,
                                            const float* __restrict__ W,
                                            const float* __restrict__ a,
                                            float* __restrict__ s1,
                                            float* __restrict__ s2,
                                            __hip_bfloat16* __restrict__ WhT){
    const int blk = blockIdx.x;            // 512 blocks, 32 rows each
    const int rowbase = blk * 32;
    const int b = blk >> 6;
    const int jt = (rowbase & (Nn-1)) >> 5;   // j-tile index within batch
    const int t = threadIdx.x;
    const int c = t & 15, r = t >> 4;

    __shared__ float hs[32*FIN];                 // 32 KB
    __shared__ __hip_bfloat16 tt[FOUT][33];      // transpose buf

    {
        const float4* h4 = (const float4*)(h + (size_t)rowbase*FIN);
        float4* l4 = (float4*)hs;
        #pragma unroll
        for (int v = 0; v < 8; ++v) l4[t + v*256] = h4[t + v*256];
    }
    __syncthreads();

    float acc0[8] = {0,0,0,0,0,0,0,0};
    float acc1[8] = {0,0,0,0,0,0,0,0};
    const float4* W4 = (const float4*)W;
    for (int k = 0; k < FIN; k += 4){
        float ha[4], hb[4];
        *(float4*)ha = *(const float4*)&hs[r*FIN + k];
        *(float4*)hb = *(const float4*)&hs[(r+16)*FIN + k];
        #pragma unroll
        for (int kk = 0; kk < 4; ++kk){
            float wv[8];
            *(float4*)&wv[0] = W4[(k+kk)*32 + c*2];
            *(float4*)&wv[4] = W4[(k+kk)*32 + c*2 + 1];
            #pragma unroll
            for (int e = 0; e < 8; ++e){
                acc0[e] += ha[kk] * wv[e];
                acc1[e] += hb[kk] * wv[e];
            }
        }
    }

    {   // s1/s2 partials over 8 cols, reduce across 16 c-lanes
        const float4* a4 = (const float4*)a;
        float a1v[8], a2v[8];
        *(float4*)&a1v[0] = a4[c*2];      *(float4*)&a1v[4] = a4[c*2+1];
        *(float4*)&a2v[0] = a4[32+c*2];   *(float4*)&a2v[4] = a4[32+c*2+1];
        float p10=0, p20=0, p11=0, p21=0;
        #pragma unroll
        for (int e = 0; e < 8; ++e){
            p10 += acc0[e]*a1v[e]; p20 += acc0[e]*a2v[e];
            p11 += acc1[e]*a1v[e]; p21 += acc1[e]*a2v[e];
        }
        #pragma unroll
        for (int m = 1; m < 16; m <<= 1){
            p10 += __shfl_xor(p10, m); p20 += __shfl_xor(p20, m);
            p11 += __shfl_xor(p11, m); p21 += __shfl_xor(p21, m);
        }
        if (c == 0){
            s1[rowbase + r]      = p10 * LOG2E;  s2[rowbase + r]      = p20 * LOG2E;
            s1[rowbase + r + 16] = p11 * LOG2E;  s2[rowbase + r + 16] = p21 * LOG2E;
        }
    }

    #pragma unroll
    for (int e = 0; e < 8; ++e){
        tt[c*8+e][r]    = __float2bfloat16(acc0[e]);
        tt[c*8+e][r+16] = __float2bfloat16(acc1[e]);
    }
    __syncthreads();
    {   // write one 8KB tile contiguously: [d][32 j]
        const int d = t >> 1, jh = (t & 1) * 16;
        short8 v0, v1;
        #pragma unroll
        for (int x = 0; x < 8; ++x){
            __hip_bfloat16 b0 = tt[d][jh + x], b1 = tt[d][jh + 8 + x];
            v0[x] = *(short*)&b0; v1[x] = *(short*)&b1;
        }
        short* Wt = (short*)WhT;
        size_t base = (((size_t)b*64 + jt)*FOUT + d)*32 + jh;
        *(short8*)&Wt[base]     = v0;
        *(short8*)&Wt[base + 8] = v1;
    }
}

// ---- K2: s1max[b] (log2-scaled domain; max is monotone) ----
__global__ __launch_bounds__(256) void k_max(const float* __restrict__ s1,
                                             float* __restrict__ s1max){
    const int b = blockIdx.x, t = threadIdx.x;
    float m = -1e30f;
    for (int i = t; i < Nn; i += 256) m = fmaxf(m, s1[b*Nn + i]);
    #pragma unroll
    for (int off = 32; off > 0; off >>= 1) m = fmaxf(m, __shfl_down(m, off));
    __shared__ float red[4];
    if ((t & 63) == 0) red[t >> 6] = m;
    __syncthreads();
    if (t == 0) s1max[b] = fmaxf(fmaxf(red[0], red[1]), fmaxf(red[2], red[3]));
}

// ---- K3: l2z[b,j] = -m_j - log2( sum_i 2^(lrelu(s1_i+s2_j) - m_j) ) ----
__global__ __launch_bounds__(256) void k_z(const float* __restrict__ s1,
                                           const float* __restrict__ s2,
                                           const float* __restrict__ s1max,
                                           float* __restrict__ l2z){
    const int b  = blockIdx.x >> 7;
    const int jt = blockIdx.x & 127;
    const int t  = threadIdx.x;
    const int jj = t & 15, part = t >> 4;
    const int j  = jt*16 + jj;
    __shared__ float s1s[Nn];
    for (int i = t; i < Nn; i += 256) s1s[i] = s1[b*Nn + i];
    __syncthreads();
    const float s2j = s2[b*Nn + j];
    const float m   = lrelu(s1max[b] + s2j);
    float sum = 0.f;
    const float4* s4 = (const float4*)&s1s[part*128];
    #pragma unroll 4
    for (int v = 0; v < 32; ++v){
        float x[4]; *(float4*)x = s4[v];
        sum += __builtin_amdgcn_exp2f(lrelu(x[0]+s2j) - m)
             + __builtin_amdgcn_exp2f(lrelu(x[1]+s2j) - m)
             + __builtin_amdgcn_exp2f(lrelu(x[2]+s2j) - m)
             + __builtin_amdgcn_exp2f(lrelu(x[3]+s2j) - m);
    }
    __shared__ float red[16][17];
    red[part][jj] = sum;
    __syncthreads();
    if (part == 0){
        float Z = 0.f;
        #pragma unroll
        for (int p = 0; p < 16; ++p) Z += red[p][jj];
        l2z[b*Nn + j] = -m - __builtin_amdgcn_logf(Z);
    }
}

// ---- K4: out = elu(P @ Wh), MFMA 16x16x32 bf16, tiled-B, no LDS ----
__global__ __launch_bounds__(256) void k_pv(const float* __restrict__ s1,
                                            const float* __restrict__ s2,
                                            const float* __restrict__ l2z,
                                            const __hip_bfloat16* __restrict__ WhT,
                                            float* __restrict__ out){
    const int b     = blockIdx.y;
    const int ibase = blockIdx.x * 64;
    const int t     = threadIdx.x;
    const int wave  = t >> 6, lane = t & 63;
    const int wm = wave & 1, wn = wave >> 1;
    const int lm = lane & 15, q = lane >> 4;

    const int i0 = ibase + wm*32 + lm;
    const float s1a = s1[(size_t)b*Nn + i0];
    const float s1b = s1[(size_t)b*Nn + i0 + 16];
    const float* s2b = s2  + (size_t)b*Nn;
    const float* lzb = l2z + (size_t)b*Nn;

    f32x4 acc[2][4];
    #pragma unroll
    for (int mt = 0; mt < 2; ++mt)
        #pragma unroll
        for (int nt = 0; nt < 4; ++nt) acc[mt][nt] = (f32x4){0.f,0.f,0.f,0.f};

    const short* Wtb = (const short*)WhT + (size_t)b*64*4096;
    int dofs[4];
    #pragma unroll
    for (int nt = 0; nt < 4; ++nt)
        dofs[nt] = (wn*64 + nt*16 + lm)*32 + q*8;

    #pragma unroll 2
    for (int jt = 0; jt < 64; ++jt){
        const int jb = jt * 32;
        const short* tile = Wtb + (size_t)jt*4096;

        short8 bfr[4];
        #pragma unroll
        for (int nt = 0; nt < 4; ++nt)
            bfr[nt] = *(const short8*)(tile + dofs[nt]);

        float s2a[8], lza[8];
        *(float4*)&s2a[0] = *(const float4*)&s2b[jb + q*8];
        *(float4*)&s2a[4] = *(const float4*)&s2b[jb + q*8 + 4];
        *(float4*)&lza[0] = *(const float4*)&lzb[jb + q*8];
        *(float4*)&lza[4] = *(const float4*)&lzb[jb + q*8 + 4];

        short8 afa, afb;
        #pragma unroll
        for (int e = 0; e < 8; ++e){
            const float z0 = s1a + s2a[e];
            const float z1 = s1b + s2a[e];
            afa[e] = bfbits(__builtin_amdgcn_exp2f(fmaxf(z0, ALPHA*z0) + lza[e]));
            afb[e] = bfbits(__builtin_amdgcn_exp2f(fmaxf(z1, ALPHA*z1) + lza[e]));
        }

        #pragma unroll
        for (int nt = 0; nt < 4; ++nt){
            acc[0][nt] = __builtin_amdgcn_mfma_f32_16x16x32_bf16(afa, bfr[nt], acc[0][nt], 0,0,0);
            acc[1][nt] = __builtin_amdgcn_mfma_f32_16x16x32_bf16(afb, bfr[nt], acc[1][nt], 0,0,0);
        }
    }

    // epilogue: ELU + f32 store. C/D: col=lane&15, row=(lane>>4)*4+reg
    #pragma unroll
    for (int mt = 0; mt < 2; ++mt){
        #pragma unroll
        for (int nt = 0; nt < 4; ++nt){
            const int col = wn*64 + nt*16 + lm;
            #pragma unroll
            for (int rg = 0; rg < 4; ++rg){
                const int row = ibase + wm*32 + mt*16 + q*4 + rg;
                const float x = acc[mt][nt][rg];
                out[((size_t)(b*Nn + row))*FOUT + col] = x > 0.f ? x : expm1f(x);
            }
        }
    }
}

extern "C" void kernel_launch(void* const* d_in, const int* in_sizes, int n_in,
                              void* d_out, int out_size, void* d_ws, size_t ws_size,
                              hipStream_t stream) {
    (void)in_sizes; (void)n_in; (void)out_size; (void)ws_size;
    const float* h = (const float*)d_in[0];
    const float* W = (const float*)d_in[1];
    const float* a = (const float*)d_in[2];
    float* out = (float*)d_out;

    float* ws    = (float*)d_ws;
    float* s1    = ws;                    // 16384
    float* s2    = s1 + Bb*Nn;            // 16384
    float* l2z   = s2 + Bb*Nn;            // 16384
    float* s1max = l2z + Bb*Nn;           // 16 (pad)
    __hip_bfloat16* WhT = (__hip_bfloat16*)(s1max + 16);  // 4 MB, tiled

    k_wh <<<dim3(Bb*Nn/32), dim3(256), 0, stream>>>(h, W, a, s1, s2, WhT);
    k_max<<<dim3(Bb),       dim3(256), 0, stream>>>(s1, s1max);
    k_z  <<<dim3(Bb*128),   dim3(256), 0, stream>>>(s1, s2, s1max, l2z);
    k_pv <<<dim3(Nn/64, Bb), dim3(256), 0, stream>>>(s1, s2, l2z, WhT, out);
}

// Round 5
// 143.087 us; speedup vs baseline: 1.0778x; 1.0778x over previous
//
#include <hip/hip_runtime.h>
#include <hip/hip_bf16.h>

// GAT layer: B=8, N=2048, Fin=256, Fout=128  (f32 in / f32 out)
// Wh = h@W ; s1 = Wh@a1 ; s2 = Wh@a2
// P[i,j] = softmax_i( lrelu(s1_i+s2_j) ) ; out = elu(P @ Wh)
// R5: k_pv restructured — 512 blocks (2/CU), 4 waves of 16ix64d, s2/l2z in
//     LDS, explicit register prefetch of B-frags. k_wh/k_z unchanged.

#define ALPHA 0.2f
#define LOG2E 1.4426950408889634f
constexpr int Bb=8, Nn=2048, FIN=256, FOUT=128;

typedef __attribute__((ext_vector_type(8))) short short8;
typedef __attribute__((ext_vector_type(4))) float f32x4;

__device__ __forceinline__ float lrelu(float x){ return fmaxf(x, ALPHA*x); }
__device__ __forceinline__ short bfbits(float x){
    __hip_bfloat16 h = __float2bfloat16(x);
    return *(short*)&h;
}

// ---- K1: Wh rows (f32) -> s1,s2 (xLOG2E), WhT tiles [b][jt][d][32] bf16 ----
__global__ __launch_bounds__(256) void k_wh(const float* __restrict__ h,
                                            const float* __restrict__ W,
                                            const float* __restrict__ a,
                                            float* __restrict__ s1,
                                            float* __restrict__ s2,
                                            __hip_bfloat16* __restrict__ WhT){
    const int blk = blockIdx.x;            // 512 blocks, 32 rows each
    const int rowbase = blk * 32;
    const int b = blk >> 6;
    const int jt = (rowbase & (Nn-1)) >> 5;
    const int t = threadIdx.x;
    const int c = t & 15, r = t >> 4;

    __shared__ float hs[32*FIN];                 // 32 KB
    __shared__ __hip_bfloat16 tt[FOUT][33];

    {
        const float4* h4 = (const float4*)(h + (size_t)rowbase*FIN);
        float4* l4 = (float4*)hs;
        #pragma unroll
        for (int v = 0; v < 8; ++v) l4[t + v*256] = h4[t + v*256];
    }
    __syncthreads();

    float acc0[8] = {0,0,0,0,0,0,0,0};
    float acc1[8] = {0,0,0,0,0,0,0,0};
    const float4* W4 = (const float4*)W;
    for (int k = 0; k < FIN; k += 4){
        float ha[4], hb[4];
        *(float4*)ha = *(const float4*)&hs[r*FIN + k];
        *(float4*)hb = *(const float4*)&hs[(r+16)*FIN + k];
        #pragma unroll
        for (int kk = 0; kk < 4; ++kk){
            float wv[8];
            *(float4*)&wv[0] = W4[(k+kk)*32 + c*2];
            *(float4*)&wv[4] = W4[(k+kk)*32 + c*2 + 1];
            #pragma unroll
            for (int e = 0; e < 8; ++e){
                acc0[e] += ha[kk] * wv[e];
                acc1[e] += hb[kk] * wv[e];
            }
        }
    }

    {
        const float4* a4 = (const float4*)a;
        float a1v[8], a2v[8];
        *(float4*)&a1v[0] = a4[c*2];      *(float4*)&a1v[4] = a4[c*2+1];
        *(float4*)&a2v[0] = a4[32+c*2];   *(float4*)&a2v[4] = a4[32+c*2+1];
        float p10=0, p20=0, p11=0, p21=0;
        #pragma unroll
        for (int e = 0; e < 8; ++e){
            p10 += acc0[e]*a1v[e]; p20 += acc0[e]*a2v[e];
            p11 += acc1[e]*a1v[e]; p21 += acc1[e]*a2v[e];
        }
        #pragma unroll
        for (int m = 1; m < 16; m <<= 1){
            p10 += __shfl_xor(p10, m); p20 += __shfl_xor(p20, m);
            p11 += __shfl_xor(p11, m); p21 += __shfl_xor(p21, m);
        }
        if (c == 0){
            s1[rowbase + r]      = p10 * LOG2E;  s2[rowbase + r]      = p20 * LOG2E;
            s1[rowbase + r + 16] = p11 * LOG2E;  s2[rowbase + r + 16] = p21 * LOG2E;
        }
    }

    #pragma unroll
    for (int e = 0; e < 8; ++e){
        tt[c*8+e][r]    = __float2bfloat16(acc0[e]);
        tt[c*8+e][r+16] = __float2bfloat16(acc1[e]);
    }
    __syncthreads();
    {
        const int d = t >> 1, jh = (t & 1) * 16;
        short8 v0, v1;
        #pragma unroll
        for (int x = 0; x < 8; ++x){
            __hip_bfloat16 b0 = tt[d][jh + x], b1 = tt[d][jh + 8 + x];
            v0[x] = *(short*)&b0; v1[x] = *(short*)&b1;
        }
        short* Wt = (short*)WhT;
        size_t base = (((size_t)b*64 + jt)*FOUT + d)*32 + jh;
        *(short8*)&Wt[base]     = v0;
        *(short8*)&Wt[base + 8] = v1;
    }
}

// ---- K2: s1max[b] ----
__global__ __launch_bounds__(256) void k_max(const float* __restrict__ s1,
                                             float* __restrict__ s1max){
    const int b = blockIdx.x, t = threadIdx.x;
    float m = -1e30f;
    for (int i = t; i < Nn; i += 256) m = fmaxf(m, s1[b*Nn + i]);
    #pragma unroll
    for (int off = 32; off > 0; off >>= 1) m = fmaxf(m, __shfl_down(m, off));
    __shared__ float red[4];
    if ((t & 63) == 0) red[t >> 6] = m;
    __syncthreads();
    if (t == 0) s1max[b] = fmaxf(fmaxf(red[0], red[1]), fmaxf(red[2], red[3]));
}

// ---- K3: l2z[b,j] = -m_j - log2(Z_j) ----
__global__ __launch_bounds__(256) void k_z(const float* __restrict__ s1,
                                           const float* __restrict__ s2,
                                           const float* __restrict__ s1max,
                                           float* __restrict__ l2z){
    const int b  = blockIdx.x >> 7;
    const int jt = blockIdx.x & 127;
    const int t  = threadIdx.x;
    const int jj = t & 15, part = t >> 4;
    const int j  = jt*16 + jj;
    __shared__ float s1s[Nn];
    for (int i = t; i < Nn; i += 256) s1s[i] = s1[b*Nn + i];
    __syncthreads();
    const float s2j = s2[b*Nn + j];
    const float m   = lrelu(s1max[b] + s2j);
    float sum = 0.f;
    const float4* s4 = (const float4*)&s1s[part*128];
    #pragma unroll 4
    for (int v = 0; v < 32; ++v){
        float x[4]; *(float4*)x = s4[v];
        sum += __builtin_amdgcn_exp2f(lrelu(x[0]+s2j) - m)
             + __builtin_amdgcn_exp2f(lrelu(x[1]+s2j) - m)
             + __builtin_amdgcn_exp2f(lrelu(x[2]+s2j) - m)
             + __builtin_amdgcn_exp2f(lrelu(x[3]+s2j) - m);
    }
    __shared__ float red[16][17];
    red[part][jj] = sum;
    __syncthreads();
    if (part == 0){
        float Z = 0.f;
        #pragma unroll
        for (int p = 0; p < 16; ++p) Z += red[p][jj];
        l2z[b*Nn + j] = -m - __builtin_amdgcn_logf(Z);
    }
}

// ---- K4: out = elu(P @ Wh), MFMA 16x16x32 bf16 ----
// 512 blocks (2/CU): 32i x 128d, 4 waves = (wm: i-tile of 16) x (wn: d-half).
// s2/l2z staged in LDS; B-frags prefetched one j-tile ahead in registers.
__global__ __launch_bounds__(256) void k_pv(const float* __restrict__ s1,
                                            const float* __restrict__ s2,
                                            const float* __restrict__ l2z,
                                            const __hip_bfloat16* __restrict__ WhT,
                                            float* __restrict__ out){
    const int b     = blockIdx.y;
    const int ibase = blockIdx.x * 32;
    const int t     = threadIdx.x;
    const int wave  = t >> 6, lane = t & 63;
    const int wm = wave & 1, wn = wave >> 1;
    const int lm = lane & 15, q = lane >> 4;

    __shared__ float s2s[Nn], lzs[Nn];   // 16 KB
    {
        const float4* g1 = (const float4*)(s2  + (size_t)b*Nn);
        const float4* g2 = (const float4*)(l2z + (size_t)b*Nn);
        float4* p1 = (float4*)s2s; float4* p2 = (float4*)lzs;
        for (int v = t; v < Nn/4; v += 256){ p1[v] = g1[v]; p2[v] = g2[v]; }
    }
    __syncthreads();

    const float s1a = s1[(size_t)b*Nn + ibase + wm*16 + lm];

    f32x4 acc[4];
    #pragma unroll
    for (int nt = 0; nt < 4; ++nt) acc[nt] = (f32x4){0.f,0.f,0.f,0.f};

    const short* Wtb = (const short*)WhT + (size_t)b*64*4096;
    int dofs[4];
    #pragma unroll
    for (int nt = 0; nt < 4; ++nt)
        dofs[nt] = (wn*64 + nt*16 + lm)*32 + q*8;

    short8 bcur[4];
    #pragma unroll
    for (int nt = 0; nt < 4; ++nt) bcur[nt] = *(const short8*)(Wtb + dofs[nt]);

    for (int jt = 0; jt < 64; ++jt){
        // prefetch next j-tile's B frags (last iter over-reads 8KB into ws pad)
        const short* tnxt = Wtb + (size_t)(jt+1)*4096;
        short8 bnxt[4];
        #pragma unroll
        for (int nt = 0; nt < 4; ++nt) bnxt[nt] = *(const short8*)(tnxt + dofs[nt]);

        const int jb = jt*32 + q*8;
        float s2a[8], lza[8];
        *(float4*)&s2a[0] = *(const float4*)&s2s[jb];
        *(float4*)&s2a[4] = *(const float4*)&s2s[jb + 4];
        *(float4*)&lza[0] = *(const float4*)&lzs[jb];
        *(float4*)&lza[4] = *(const float4*)&lzs[jb + 4];

        short8 afa;
        #pragma unroll
        for (int e = 0; e < 8; ++e){
            const float z = s1a + s2a[e];
            afa[e] = bfbits(__builtin_amdgcn_exp2f(fmaxf(z, ALPHA*z) + lza[e]));
        }

        #pragma unroll
        for (int nt = 0; nt < 4; ++nt)
            acc[nt] = __builtin_amdgcn_mfma_f32_16x16x32_bf16(afa, bcur[nt], acc[nt], 0,0,0);

        #pragma unroll
        for (int nt = 0; nt < 4; ++nt) bcur[nt] = bnxt[nt];
    }

    // epilogue: ELU + f32 store. C/D: col=lane&15, row=(lane>>4)*4+reg
    #pragma unroll
    for (int nt = 0; nt < 4; ++nt){
        const int col = wn*64 + nt*16 + lm;
        #pragma unroll
        for (int rg = 0; rg < 4; ++rg){
            const int row = ibase + wm*16 + q*4 + rg;
            const float x = acc[nt][rg];
            out[((size_t)(b*Nn + row))*FOUT + col] = x > 0.f ? x : expm1f(x);
        }
    }
}

extern "C" void kernel_launch(void* const* d_in, const int* in_sizes, int n_in,
                              void* d_out, int out_size, void* d_ws, size_t ws_size,
                              hipStream_t stream) {
    (void)in_sizes; (void)n_in; (void)out_size; (void)ws_size;
    const float* h = (const float*)d_in[0];
    const float* W = (const float*)d_in[1];
    const float* a = (const float*)d_in[2];
    float* out = (float*)d_out;

    float* ws    = (float*)d_ws;
    float* s1    = ws;                    // 16384
    float* s2    = s1 + Bb*Nn;            // 16384
    float* l2z   = s2 + Bb*Nn;            // 16384
    float* s1max = l2z + Bb*Nn;           // 16 (pad)
    __hip_bfloat16* WhT = (__hip_bfloat16*)(s1max + 16);  // 4 MB tiled (+8KB overread pad lives in ws)

    k_wh <<<dim3(Bb*Nn/32), dim3(256), 0, stream>>>(h, W, a, s1, s2, WhT);
    k_max<<<dim3(Bb),       dim3(256), 0, stream>>>(s1, s1max);
    k_z  <<<dim3(Bb*128),   dim3(256), 0, stream>>>(s1, s2, s1max, l2z);
    k_pv <<<dim3(Nn/32, Bb), dim3(256), 0, stream>>>(s1, s2, l2z, WhT, out);
}

// Round 6
// 125.312 us; speedup vs baseline: 1.2306x; 1.1418x over previous
//
#include <hip/hip_runtime.h>
#include <hip/hip_bf16.h>

// GAT layer: B=8, N=2048, Fin=256, Fout=128  (f32 in / f32 out)
// Wh = h@W ; s1 = Wh@a1 ; s2 = Wh@a2
// P[i,j] = softmax_i( lrelu(s1_i+s2_j) ) ; out = elu(P @ Wh)
// R6: (1) k_wh on MFMA bf16 (B from pre-tiled WT_t, prep kernel);
//     (2) k_pv 8-wave blocks, K-split kh=2, LDS combine -> 4 waves/SIMD;
//         j-loop unroll x2 with ping-pong B prefetch.

#define ALPHA 0.2f
#define LOG2E 1.4426950408889634f
constexpr int Bb=8, Nn=2048, FIN=256, FOUT=128;

typedef __attribute__((ext_vector_type(8))) short short8;
typedef __attribute__((ext_vector_type(4))) float f32x4;

__device__ __forceinline__ float lrelu(float x){ return fmaxf(x, ALPHA*x); }
__device__ __forceinline__ unsigned short bfbits(float x){
    __hip_bfloat16 h = __float2bfloat16(x);
    return *(unsigned short*)&h;
}

// ---- K0: WT_t[kt][n][32] bf16 from W f32 (kt=k/32, n=col, kk=k%32) ----
__global__ __launch_bounds__(256) void k_prep(const float* __restrict__ W,
                                              __hip_bfloat16* __restrict__ WTt){
    const int idx = blockIdx.x*256 + threadIdx.x;   // 32 blocks
    #pragma unroll
    for (int v = 0; v < 4; ++v){
        const int widx = idx + v*8192;
        const int kk = widx & 31, n = (widx>>5)&127, kt = widx>>12;
        WTt[widx] = __float2bfloat16(W[(kt*32+kk)*FOUT + n]);
    }
}

// ---- K1: Wh = h@W via MFMA -> s1,s2 (xLOG2E), WhT tiles [b][jt][d][32] ----
// 512 blocks x 32 rows, 4 waves: wm = row-half(16), wn = col-half(64).
__global__ __launch_bounds__(256) void k_wh(const float* __restrict__ h,
                                            const float* __restrict__ a,
                                            const __hip_bfloat16* __restrict__ WTt,
                                            float* __restrict__ s1,
                                            float* __restrict__ s2,
                                            __hip_bfloat16* __restrict__ WhT){
    const int blk = blockIdx.x;            // 512
    const int rowbase = blk * 32;
    const int b = blk >> 6;
    const int jt = (rowbase & (Nn-1)) >> 5;
    const int t = threadIdx.x;
    const int wave = t>>6, lane = t&63;
    const int wm = wave & 1, wn = wave >> 1;
    const int lm = lane & 15, q = lane >> 4;

    __shared__ unsigned short hsb[32*264];      // 32 rows x 264 (pad+8) bf16
    __shared__ unsigned short tt[32*136];       // Wh bf16 [row][d] pad
    __shared__ float s1red[2][32], s2red[2][32];

    {   // stage h tile f32 -> bf16 LDS
        const float4* h4 = (const float4*)(h + (size_t)rowbase*FIN);
        for (int v = t; v < 2048; v += 256){
            const int row = v >> 6, kq = v & 63;
            float4 x = h4[v];
            ushort4 u;
            u.x = bfbits(x.x); u.y = bfbits(x.y);
            u.z = bfbits(x.z); u.w = bfbits(x.w);
            *(ushort4*)&hsb[row*264 + kq*4] = u;
        }
    }
    __syncthreads();

    f32x4 acc[4];
    #pragma unroll
    for (int ntl = 0; ntl < 4; ++ntl) acc[ntl] = (f32x4){0.f,0.f,0.f,0.f};

    const short* Wt = (const short*)WTt;
    #pragma unroll 2
    for (int kt = 0; kt < 8; ++kt){
        const short8 afr = *(const short8*)&hsb[(wm*16+lm)*264 + kt*32 + q*8];
        #pragma unroll
        for (int ntl = 0; ntl < 4; ++ntl){
            const short8 bfr = *(const short8*)(Wt + ((kt*128 + wn*64 + ntl*16 + lm)*32 + q*8));
            acc[ntl] = __builtin_amdgcn_mfma_f32_16x16x32_bf16(afr, bfr, acc[ntl], 0,0,0);
        }
    }

    {   // s1/s2: per-rg dot with a over this wave's 64 cols, lm-reduce
        float a1v[4], a2v[4];
        #pragma unroll
        for (int ntl = 0; ntl < 4; ++ntl){
            a1v[ntl] = a[wn*64 + ntl*16 + lm];
            a2v[ntl] = a[FOUT + wn*64 + ntl*16 + lm];
        }
        #pragma unroll
        for (int rg = 0; rg < 4; ++rg){
            float p1 = 0.f, p2 = 0.f;
            #pragma unroll
            for (int ntl = 0; ntl < 4; ++ntl){
                p1 += acc[ntl][rg]*a1v[ntl];
                p2 += acc[ntl][rg]*a2v[ntl];
            }
            #pragma unroll
            for (int m = 1; m < 16; m <<= 1){
                p1 += __shfl_xor(p1, m);
                p2 += __shfl_xor(p2, m);
            }
            if (lm == 0){
                s1red[wn][wm*16 + q*4 + rg] = p1;
                s2red[wn][wm*16 + q*4 + rg] = p2;
            }
        }
    }

    // C -> tt (bf16, [row][d])
    #pragma unroll
    for (int ntl = 0; ntl < 4; ++ntl)
        #pragma unroll
        for (int rg = 0; rg < 4; ++rg)
            tt[(wm*16 + q*4 + rg)*136 + wn*64 + ntl*16 + lm] = bfbits(acc[ntl][rg]);
    __syncthreads();

    if (t < 32){
        s1[rowbase + t] = (s1red[0][t] + s1red[1][t]) * LOG2E;
        s2[rowbase + t] = (s2red[0][t] + s2red[1][t]) * LOG2E;
    }
    {   // WhT tile write: [b][jt][d][32 j]
        const int d = t >> 1, jh = (t & 1) * 16;
        short8 v0, v1;
        #pragma unroll
        for (int x = 0; x < 8; ++x){
            v0[x] = (short)tt[(jh + x)*136 + d];
            v1[x] = (short)tt[(jh + 8 + x)*136 + d];
        }
        short* Wo = (short*)WhT;
        const size_t base = (((size_t)b*64 + jt)*FOUT + d)*32 + jh;
        *(short8*)&Wo[base]     = v0;
        *(short8*)&Wo[base + 8] = v1;
    }
}

// ---- K2: s1max[b] ----
__global__ __launch_bounds__(256) void k_max(const float* __restrict__ s1,
                                             float* __restrict__ s1max){
    const int b = blockIdx.x, t = threadIdx.x;
    float m = -1e30f;
    for (int i = t; i < Nn; i += 256) m = fmaxf(m, s1[b*Nn + i]);
    #pragma unroll
    for (int off = 32; off > 0; off >>= 1) m = fmaxf(m, __shfl_down(m, off));
    __shared__ float red[4];
    if ((t & 63) == 0) red[t >> 6] = m;
    __syncthreads();
    if (t == 0) s1max[b] = fmaxf(fmaxf(red[0], red[1]), fmaxf(red[2], red[3]));
}

// ---- K3: l2z[b,j] = -m_j - log2(Z_j)   (log2 domain) ----
__global__ __launch_bounds__(256) void k_z(const float* __restrict__ s1,
                                           const float* __restrict__ s2,
                                           const float* __restrict__ s1max,
                                           float* __restrict__ l2z){
    const int b  = blockIdx.x >> 7;
    const int jt = blockIdx.x & 127;
    const int t  = threadIdx.x;
    const int jj = t & 15, part = t >> 4;
    const int j  = jt*16 + jj;
    __shared__ float s1s[Nn];
    for (int i = t; i < Nn; i += 256) s1s[i] = s1[b*Nn + i];
    __syncthreads();
    const float s2j = s2[b*Nn + j];
    const float m   = lrelu(s1max[b] + s2j);
    float sum = 0.f;
    const float4* s4 = (const float4*)&s1s[part*128];
    #pragma unroll 4
    for (int v = 0; v < 32; ++v){
        float x[4]; *(float4*)x = s4[v];
        sum += __builtin_amdgcn_exp2f(lrelu(x[0]+s2j) - m)
             + __builtin_amdgcn_exp2f(lrelu(x[1]+s2j) - m)
             + __builtin_amdgcn_exp2f(lrelu(x[2]+s2j) - m)
             + __builtin_amdgcn_exp2f(lrelu(x[3]+s2j) - m);
    }
    __shared__ float red[16][17];
    red[part][jj] = sum;
    __syncthreads();
    if (part == 0){
        float Z = 0.f;
        #pragma unroll
        for (int p = 0; p < 16; ++p) Z += red[p][jj];
        l2z[b*Nn + j] = -m - __builtin_amdgcn_logf(Z);   // v_log_f32 = log2
    }
}

// ---- K4: out = elu(P @ Wh), MFMA, 8 waves (wm x wn x kh), K-split ----
__global__ __launch_bounds__(512, 4) void k_pv(const float* __restrict__ s1,
                                               const float* __restrict__ s2,
                                               const float* __restrict__ l2z,
                                               const __hip_bfloat16* __restrict__ WhT,
                                               float* __restrict__ out){
    const int b     = blockIdx.y;
    const int ibase = blockIdx.x * 32;
    const int t     = threadIdx.x;
    const int wave  = t >> 6, lane = t & 63;
    const int wm = wave & 1, wn = (wave >> 1) & 1, kh = wave >> 2;
    const int lm = lane & 15, q = lane >> 4;

    __shared__ float s2s[Nn], lzs[Nn];        // 16 KB
    __shared__ float comb[32][128];           // 16 KB partial-combine
    {
        const float4* g1 = (const float4*)(s2  + (size_t)b*Nn);
        const float4* g2 = (const float4*)(l2z + (size_t)b*Nn);
        float4* p1 = (float4*)s2s; float4* p2 = (float4*)lzs;
        for (int v = t; v < Nn/4; v += 512){ p1[v] = g1[v]; p2[v] = g2[v]; }
    }
    __syncthreads();

    const float s1a = s1[(size_t)b*Nn + ibase + wm*16 + lm];

    f32x4 acc[4];
    #pragma unroll
    for (int nt = 0; nt < 4; ++nt) acc[nt] = (f32x4){0.f,0.f,0.f,0.f};

    const short* Wtb = (const short*)WhT + (size_t)b*64*4096;
    int dofs[4];
    #pragma unroll
    for (int nt = 0; nt < 4; ++nt)
        dofs[nt] = (wn*64 + nt*16 + lm)*32 + q*8;

    const int jt0 = kh*32;
    short8 bb0[4], bb1[4];
    #pragma unroll
    for (int nt = 0; nt < 4; ++nt)
        bb0[nt] = *(const short8*)(Wtb + (size_t)jt0*4096 + dofs[nt]);

    for (int jt = jt0; jt < jt0 + 32; jt += 2){
        {   // prefetch jt+1
            const short* tn = Wtb + (size_t)(jt+1)*4096;
            #pragma unroll
            for (int nt = 0; nt < 4; ++nt) bb1[nt] = *(const short8*)(tn + dofs[nt]);
        }
        {   // P(jt) + MFMA(bb0)
            const int jb = jt*32 + q*8;
            float s2a[8], lza[8];
            *(float4*)&s2a[0] = *(const float4*)&s2s[jb];
            *(float4*)&s2a[4] = *(const float4*)&s2s[jb+4];
            *(float4*)&lza[0] = *(const float4*)&lzs[jb];
            *(float4*)&lza[4] = *(const float4*)&lzs[jb+4];
            short8 afa;
            #pragma unroll
            for (int e = 0; e < 8; ++e){
                const float z = s1a + s2a[e];
                afa[e] = (short)bfbits(__builtin_amdgcn_exp2f(fmaxf(z, ALPHA*z) + lza[e]));
            }
            #pragma unroll
            for (int nt = 0; nt < 4; ++nt)
                acc[nt] = __builtin_amdgcn_mfma_f32_16x16x32_bf16(afa, bb0[nt], acc[nt], 0,0,0);
        }
        {   // prefetch jt+2 (last iter over-reads 1 tile into ws pad)
            const short* tn = Wtb + (size_t)(jt+2)*4096;
            #pragma unroll
            for (int nt = 0; nt < 4; ++nt) bb0[nt] = *(const short8*)(tn + dofs[nt]);
        }
        {   // P(jt+1) + MFMA(bb1)
            const int jb = (jt+1)*32 + q*8;
            float s2a[8], lza[8];
            *(float4*)&s2a[0] = *(const float4*)&s2s[jb];
            *(float4*)&s2a[4] = *(const float4*)&s2s[jb+4];
            *(float4*)&lza[0] = *(const float4*)&lzs[jb];
            *(float4*)&lza[4] = *(const float4*)&lzs[jb+4];
            short8 afa;
            #pragma unroll
            for (int e = 0; e < 8; ++e){
                const float z = s1a + s2a[e];
                afa[e] = (short)bfbits(__builtin_amdgcn_exp2f(fmaxf(z, ALPHA*z) + lza[e]));
            }
            #pragma unroll
            for (int nt = 0; nt < 4; ++nt)
                acc[nt] = __builtin_amdgcn_mfma_f32_16x16x32_bf16(afa, bb1[nt], acc[nt], 0,0,0);
        }
    }

    // K-split combine: kh=0 writes partials, kh=1 adds + ELU + store
    if (kh == 0){
        #pragma unroll
        for (int nt = 0; nt < 4; ++nt)
            #pragma unroll
            for (int rg = 0; rg < 4; ++rg)
                comb[wm*16 + q*4 + rg][wn*64 + nt*16 + lm] = acc[nt][rg];
    }
    __syncthreads();
    if (kh == 1){
        #pragma unroll
        for (int nt = 0; nt < 4; ++nt){
            const int col = wn*64 + nt*16 + lm;
            #pragma unroll
            for (int rg = 0; rg < 4; ++rg){
                const int row = wm*16 + q*4 + rg;
                const float x = acc[nt][rg] + comb[row][col];
                out[((size_t)(b*Nn + ibase + row))*FOUT + col] = x > 0.f ? x : expm1f(x);
            }
        }
    }
}

extern "C" void kernel_launch(void* const* d_in, const int* in_sizes, int n_in,
                              void* d_out, int out_size, void* d_ws, size_t ws_size,
                              hipStream_t stream) {
    (void)in_sizes; (void)n_in; (void)out_size; (void)ws_size;
    const float* h = (const float*)d_in[0];
    const float* W = (const float*)d_in[1];
    const float* a = (const float*)d_in[2];
    float* out = (float*)d_out;

    float* ws    = (float*)d_ws;
    float* s1    = ws;                    // 16384
    float* s2    = s1 + Bb*Nn;            // 16384
    float* l2z   = s2 + Bb*Nn;            // 16384
    float* s1max = l2z + Bb*Nn;           // 16
    __hip_bfloat16* WTt = (__hip_bfloat16*)(s1max + 16);   // 32768 bf16 = 64 KB
    __hip_bfloat16* WhT = WTt + 32768;                     // 4 MB tiled (+8KB overread pad in ws)

    k_prep<<<dim3(32),       dim3(256), 0, stream>>>(W, WTt);
    k_wh  <<<dim3(Bb*Nn/32), dim3(256), 0, stream>>>(h, a, WTt, s1, s2, WhT);
    k_max <<<dim3(Bb),       dim3(256), 0, stream>>>(s1, s1max);
    k_z   <<<dim3(Bb*128),   dim3(256), 0, stream>>>(s1, s2, s1max, l2z);
    k_pv  <<<dim3(Nn/32, Bb), dim3(512), 0, stream>>>(s1, s2, l2z, WhT, out);
}